// Round 2
// baseline (526.618 us; speedup 1.0000x reference)
//
#include <hip/hip_runtime.h>
#include <hip/hip_bf16.h>

typedef __attribute__((ext_vector_type(8))) short short8;       // MFMA A/B frag (8 bf16)
typedef __attribute__((ext_vector_type(4))) float f32x4;        // MFMA C/D frag
typedef __attribute__((ext_vector_type(8))) unsigned short ushort8;

#define LDS_ASYNC16(gsrc, ldst) \
  __builtin_amdgcn_global_load_lds((const __attribute__((address_space(1))) void*)(gsrc), \
                                   (__attribute__((address_space(3))) void*)(ldst), 16, 0, 0)

__device__ __forceinline__ unsigned short f2bf(float f) {
  unsigned int u = __float_as_uint(f);
  unsigned int r = (u + 0x7FFFu + ((u >> 16) & 1u)) >> 16;   // RNE
  return (unsigned short)r;
}

// ---------------- cast fp32 -> bf16 (vectorized) ----------------
__global__ __launch_bounds__(256) void cast_f32_bf16(const float* __restrict__ in,
                                                     unsigned short* __restrict__ out, int n) {
  int i = (blockIdx.x * 256 + threadIdx.x) * 8;
  if (i >= n) return;
  float4 a = *(const float4*)(in + i);
  float4 b = *(const float4*)(in + i + 4);
  ushort8 o;
  o[0] = f2bf(a.x); o[1] = f2bf(a.y); o[2] = f2bf(a.z); o[3] = f2bf(a.w);
  o[4] = f2bf(b.x); o[5] = f2bf(b.y); o[6] = f2bf(b.z); o[7] = f2bf(b.w);
  *(ushort8*)(out + i) = o;
}

// ---- V transpose (per group of 4 heads): src rows=2048 tokens (stride 4096),
// ---- slot z picks head col block z*512. Out: Vt[z][512(d)][2048(k)] ----
__global__ __launch_bounds__(256) void transpose_v(const unsigned short* __restrict__ V,
                                                   unsigned short* __restrict__ Vt) {
  __shared__ unsigned short t[64][72];   // 72*2B=144B row stride = 9*16B, keeps 16B alignment
  int slot = blockIdx.z;
  int k0 = blockIdx.x << 6, d0 = blockIdx.y << 6;
  const unsigned short* src = V + (size_t)k0 * 4096 + slot * 512 + d0;
  int rr = threadIdx.x >> 3;            // 0..31
  int cc = (threadIdx.x & 7) << 3;      // 0,8,..,56
#pragma unroll
  for (int half = 0; half < 64; half += 32) {
    int r = rr + half;
    ushort8 v = *(const ushort8*)(src + (size_t)r * 4096 + cc);
#pragma unroll
    for (int e = 0; e < 8; ++e) t[cc + e][r] = v[e];
  }
  __syncthreads();
  unsigned short* dst = Vt + ((size_t)slot * 512 + d0) * 2048 + k0;
#pragma unroll
  for (int half = 0; half < 64; half += 32) {
    int d = rr + half;
    *(ushort8*)(dst + (size_t)d * 2048 + cc) = *(const ushort8*)&t[d][cc];
  }
}

// ---------------- causal softmax, fp32 scores -> bf16 P in-place ----------------
__global__ __launch_bounds__(256) void softmax_causal(float* __restrict__ S) {
  int row = blockIdx.x;          // slot*2048 + q
  int q = row & 2047;
  float* srow = S + (size_t)row * 2048;
  unsigned short* prow = (unsigned short*)srow;   // bf16 row aliased over fp32 row bytes
  int n = q + 1;
  int t = threadIdx.x;
  int wave = t >> 6, lane = t & 63;
  float vals[8];
  float m = -1e30f;
#pragma unroll
  for (int j = 0; j < 8; ++j) {
    int idx = j * 256 + t;
    vals[j] = (idx < n) ? srow[idx] : -1e30f;
    m = fmaxf(m, vals[j]);
  }
#pragma unroll
  for (int off = 32; off > 0; off >>= 1) m = fmaxf(m, __shfl_xor(m, off, 64));
  __shared__ float red[8];
  if (lane == 0) red[wave] = m;
  __syncthreads();
  m = fmaxf(fmaxf(red[0], red[1]), fmaxf(red[2], red[3]));
  float s = 0.f;
#pragma unroll
  for (int j = 0; j < 8; ++j) {
    int idx = j * 256 + t;
    float e = (idx < n) ? __expf(vals[j] - m) : 0.f;
    vals[j] = e; s += e;
  }
#pragma unroll
  for (int off = 32; off > 0; off >>= 1) s += __shfl_xor(s, off, 64);
  if (lane == 0) red[4 + wave] = s;
  __syncthreads();
  s = red[4] + red[5] + red[6] + red[7];
  float inv = 1.0f / s;
#pragma unroll
  for (int j = 0; j < 8; ++j) {   // all srow reads happened before the barriers; alias-write safe
    int idx = j * 256 + t;
    prow[idx] = f2bf(vals[j] * inv);       // exact zeros for idx >= n
  }
}

// ---------------- bf16 GEMM: C = A * B^T   (A:[M,K] lda, B:[N,K] ldb, row-major bf16) ----------------
// m97 structure: 128x128 tile, BK=64, 4 waves of 64x64, mfma_f32_16x16x32_bf16, global_load_lds w16.
template<int OUT_F32, int CSKIP, int KCLIP>
__global__ __launch_bounds__(256, 2) void gemm_bt(
    const unsigned short* __restrict__ A, const unsigned short* __restrict__ B,
    void* __restrict__ C, int K, int lda, int ldb, int ldc, int nH,
    long long sAb, long long sAh, long long sBb, long long sBh,
    long long sCb, long long sCh, float scale)
{
  __shared__ unsigned short As[128 * 64];
  __shared__ unsigned short Bs[128 * 64];
  int m0 = blockIdx.y * 128, n0 = blockIdx.x * 128;
  if (CSKIP && n0 > m0) return;                 // fully-masked causal tile
  int z = blockIdx.z;
  int zb = z / nH, zh = z - zb * nH;
  const unsigned short* Ap = A + (size_t)(zb * sAb + zh * sAh);
  const unsigned short* Bp = B + (size_t)(zb * sBb + zh * sBh);
  size_t coff = (size_t)(zb * sCb + zh * sCh);
  int tid = threadIdx.x;
  int wave = tid >> 6, lane = tid & 63;
  int kEnd = KCLIP ? min(K, m0 + 128) : K;

  int wr = (wave >> 1) * 64, wc = (wave & 1) * 64;  // 2x2 wave grid, 64x64 each
  int lr = lane & 15;
  int lkb = (lane >> 4) * 8;

  f32x4 acc[4][4] = {};

  for (int k0 = 0; k0 < kEnd; k0 += 64) {
#pragma unroll
    for (int it = 0; it < 4; ++it) {
      int g = it * 256 + tid;                  // granule 0..1023 (16B each)
      int r = g >> 3, c = (g & 7) << 3;
      LDS_ASYNC16(Ap + (size_t)(m0 + r) * lda + (k0 + c), As + (size_t)(it * 256 + wave * 64) * 8);
      LDS_ASYNC16(Bp + (size_t)(n0 + r) * ldb + (k0 + c), Bs + (size_t)(it * 256 + wave * 64) * 8);
    }
    __syncthreads();
#pragma unroll
    for (int kk = 0; kk < 64; kk += 32) {
      short8 a[4], b[4];
#pragma unroll
      for (int i = 0; i < 4; ++i)
        a[i] = *(const short8*)(As + (size_t)(wr + i * 16 + lr) * 64 + kk + lkb);
#pragma unroll
      for (int j = 0; j < 4; ++j)
        b[j] = *(const short8*)(Bs + (size_t)(wc + j * 16 + lr) * 64 + kk + lkb);
#pragma unroll
      for (int i = 0; i < 4; ++i)
#pragma unroll
        for (int j = 0; j < 4; ++j)
          acc[i][j] = __builtin_amdgcn_mfma_f32_16x16x32_bf16(a[i], b[j], acc[i][j], 0, 0, 0);
    }
    __syncthreads();
  }

  int orow = (lane >> 4) * 4, ocol = lane & 15;   // C/D: col=lane&15, row=(lane>>4)*4+reg
#pragma unroll
  for (int i = 0; i < 4; ++i)
#pragma unroll
    for (int j = 0; j < 4; ++j)
#pragma unroll
      for (int r = 0; r < 4; ++r) {
        int row = m0 + wr + i * 16 + orow + r;
        int col = n0 + wc + j * 16 + ocol;
        float v = acc[i][j][r] * scale;
        if (OUT_F32) ((float*)C)[coff + (size_t)row * ldc + col] = v;
        else ((unsigned short*)C)[coff + (size_t)row * ldc + col] = f2bf(v);
      }
}

// ---------------- launcher ----------------
extern "C" void kernel_launch(void* const* d_in, const int* in_sizes, int n_in,
                              void* d_out, int out_size, void* d_ws, size_t ws_size,
                              hipStream_t stream) {
  const float* x  = (const float*)d_in[0];
  // d_in[1] = attn_mask (causal; handled analytically)
  const float* Wq = (const float*)d_in[2];
  const float* Wk = (const float*)d_in[3];
  const float* Wv = (const float*)d_in[4];
  const float* Wo = (const float*)d_in[5];

  // workspace layout (188 MB total):
  //  [0,4)    xb   bf16 [4096][512]
  //  [4,16)   Wqkv bf16 [3][4096][512]
  //  [16,20)  Wob  bf16 [512][4096]
  //  [20,116) QKV  bf16 [3][4096][4096]   (Q region doubles as attention-out AO)
  //  [116,180) Sc  fp32 [4][2048][2048]   (per-group scores; softmax -> bf16 P in place)
  //  [180,188) VtG bf16 [4][512][2048]    (per-group transposed V)
  if (ws_size < (size_t)188 * (1 << 20)) return;   // graceful: leaves d_out=0 as diagnostic

  char* ws = (char*)d_ws;
  unsigned short* xb   = (unsigned short*)(ws);
  unsigned short* Wqkv = (unsigned short*)(ws + (size_t)4   * (1 << 20));
  unsigned short* Wob  = (unsigned short*)(ws + (size_t)16  * (1 << 20));
  unsigned short* QKV  = (unsigned short*)(ws + (size_t)20  * (1 << 20));
  float*          Sc   = (float*)(ws + (size_t)116 * (1 << 20));
  unsigned short* VtG  = (unsigned short*)(ws + (size_t)180 * (1 << 20));

  const int NEw = 4096 * 512;       // elements per weight matrix / x
  const int NEm = 4096 * 4096;      // elements per Q/K/V matrix

  // 1) casts
  cast_f32_bf16<<<dim3(NEw / 2048), 256, 0, stream>>>(x,  xb, NEw);
  cast_f32_bf16<<<dim3(NEw / 2048), 256, 0, stream>>>(Wq, Wqkv,           NEw);
  cast_f32_bf16<<<dim3(NEw / 2048), 256, 0, stream>>>(Wk, Wqkv + NEw,     NEw);
  cast_f32_bf16<<<dim3(NEw / 2048), 256, 0, stream>>>(Wv, Wqkv + 2 * NEw, NEw);
  cast_f32_bf16<<<dim3(NEw / 2048), 256, 0, stream>>>(Wo, Wob, NEw);

  // 2) QKV projection: [4096,512] x [4096,512]^T -> [3][4096][4096] bf16
  gemm_bt<0, 0, 0><<<dim3(32, 32, 3), 256, 0, stream>>>(
      xb, Wqkv, QKV, 512, 512, 512, 4096, 3,
      0LL, 0LL, 0LL, (long long)NEw, 0LL, (long long)NEm, 1.0f);

  // 3) attention, 4 groups of 4 heads: group g = (b = g>>1, head-quad hq = g&1)
  for (int g = 0; g < 4; ++g) {
    int b = g >> 1, hq = g & 1;
    size_t tokOff = (size_t)b * 2048 * 4096;
    size_t colOff = (size_t)hq * 2048;               // hq*4 heads * 512
    const unsigned short* Qb = QKV + tokOff + colOff;
    const unsigned short* Kb = QKV + NEm + tokOff + colOff;
    const unsigned short* Vb = QKV + 2 * (size_t)NEm + tokOff + colOff;
    unsigned short* AOb = QKV + tokOff + colOff;     // AO aliases Q (safe: per-head Q dead)

    // 3a) scores = Q K^T / sqrt(512) (fp32, causal tile skip), slot zh = head in quad
    gemm_bt<1, 1, 0><<<dim3(16, 16, 4), 256, 0, stream>>>(
        Qb, Kb, Sc, 512, 4096, 4096, 2048, 4,
        0LL, 512LL, 0LL, 512LL, 0LL, 2048LL * 2048, 0.04419417382415922f);

    // 3b) V transpose for this group
    transpose_v<<<dim3(32, 8, 4), 256, 0, stream>>>(Vb, VtG);

    // 3c) softmax (causal) -> P bf16 in place (bf16 row stride 4096)
    softmax_causal<<<dim3(4 * 2048), 256, 0, stream>>>(Sc);

    // 3d) O = P @ V via P * Vt^T, k clipped to m0+128
    gemm_bt<0, 0, 1><<<dim3(4, 16, 4), 256, 0, stream>>>(
        (const unsigned short*)Sc, VtG, AOb, 2048, 4096, 2048, 4096, 4,
        0LL, 2048LL * 4096, 0LL, 512LL * 2048, 0LL, 512LL, 1.0f);
  }

  // 4) out = AO @ Wo^T -> fp32 d_out [4096][512]
  gemm_bt<1, 0, 0><<<dim3(4, 32, 1), 256, 0, stream>>>(
      QKV, Wob, d_out, 4096, 4096, 4096, 512, 1,
      0LL, 0LL, 0LL, 0LL, 0LL, 0LL, 1.0f);
}

// Round 4
// 352.752 us; speedup vs baseline: 1.4929x; 1.4929x over previous
//
#include <hip/hip_runtime.h>
#include <hip/hip_bf16.h>

typedef __attribute__((ext_vector_type(8))) short short8;       // MFMA A/B frag (8 bf16)
typedef __attribute__((ext_vector_type(4))) float f32x4;        // MFMA C/D frag
typedef __attribute__((ext_vector_type(8))) unsigned short ushort8;

#define LDS_ASYNC16(gsrc, ldst) \
  __builtin_amdgcn_global_load_lds((const __attribute__((address_space(1))) void*)(gsrc), \
                                   (__attribute__((address_space(3))) void*)(ldst), 16, 0, 0)

__device__ __forceinline__ unsigned short f2bf(float f) {
  unsigned int u = __float_as_uint(f);
  unsigned int r = (u + 0x7FFFu + ((u >> 16) & 1u)) >> 16;   // RNE
  return (unsigned short)r;
}
__device__ __forceinline__ float bf2f(unsigned short h) {
  return __uint_as_float((unsigned int)h << 16);
}

// ---------------- fused cast fp32 -> bf16, 5 tensors via z ----------------
__global__ __launch_bounds__(256) void cast5_f32_bf16(
    const float* __restrict__ i0, const float* __restrict__ i1, const float* __restrict__ i2,
    const float* __restrict__ i3, const float* __restrict__ i4,
    unsigned short* __restrict__ out /* 5 contiguous 2Mi-elem regions */) {
  const float* src[5] = {i0, i1, i2, i3, i4};
  int z = blockIdx.z;
  const float* in = src[z];
  size_t i = ((size_t)blockIdx.x * 256 + threadIdx.x) * 8;
  float4 a = *(const float4*)(in + i);
  float4 b = *(const float4*)(in + i + 4);
  ushort8 o;
  o[0] = f2bf(a.x); o[1] = f2bf(a.y); o[2] = f2bf(a.z); o[3] = f2bf(a.w);
  o[4] = f2bf(b.x); o[5] = f2bf(b.y); o[6] = f2bf(b.z); o[7] = f2bf(b.w);
  *(ushort8*)(out + (size_t)z * 2097152 + i) = o;
}

// ---- V transpose (8 heads/group): slot z picks head col block z*512.
// ---- src rows = 2048 tokens (stride 4096). Out: Vt[z][512(d)][2048(k)] ----
__global__ __launch_bounds__(256) void transpose_v(const unsigned short* __restrict__ V,
                                                   unsigned short* __restrict__ Vt) {
  __shared__ unsigned short t[64][72];   // 144B row stride (9x16B) keeps 16B alignment
  int slot = blockIdx.z;
  int k0 = blockIdx.x << 6, d0 = blockIdx.y << 6;
  const unsigned short* src = V + (size_t)k0 * 4096 + slot * 512 + d0;
  int rr = threadIdx.x >> 3;            // 0..31
  int cc = (threadIdx.x & 7) << 3;      // 0,8,..,56
#pragma unroll
  for (int half = 0; half < 64; half += 32) {
    int r = rr + half;
    ushort8 v = *(const ushort8*)(src + (size_t)r * 4096 + cc);
#pragma unroll
    for (int e = 0; e < 8; ++e) t[cc + e][r] = v[e];
  }
  __syncthreads();
  unsigned short* dst = Vt + ((size_t)slot * 512 + d0) * 2048 + k0;
#pragma unroll
  for (int half = 0; half < 64; half += 32) {
    int d = rr + half;
    *(ushort8*)(dst + (size_t)d * 2048 + cc) = *(const ushort8*)&t[d][cc];
  }
}

// ---------------- causal softmax, bf16 scores -> bf16 P in place ----------------
// Row q: reads 2048 bf16, masks k>q, writes P for k < nW=(q/128+1)*128 (zeros past q),
// leaving exactly the region PV's KCLIP loop will read.
__global__ __launch_bounds__(256) void softmax_causal_bf16(unsigned short* __restrict__ S) {
  int row = blockIdx.x;          // slot*2048 + q
  int q = row & 2047;
  unsigned short* srow = S + (size_t)row * 2048;
  int n = q + 1;
  int nW = ((q >> 7) + 1) << 7;
  int t = threadIdx.x, wave = t >> 6, lane = t & 63;
  int base = t * 8;
  ushort8 u = *(const ushort8*)(srow + base);
  float vals[8];
  float m = -1e30f;
#pragma unroll
  for (int e = 0; e < 8; ++e) {
    float v = bf2f(u[e]);
    vals[e] = (base + e < n) ? v : -1e30f;
    m = fmaxf(m, vals[e]);
  }
#pragma unroll
  for (int off = 32; off > 0; off >>= 1) m = fmaxf(m, __shfl_xor(m, off, 64));
  __shared__ float red[8];
  if (lane == 0) red[wave] = m;
  __syncthreads();
  m = fmaxf(fmaxf(red[0], red[1]), fmaxf(red[2], red[3]));
  float s = 0.f;
#pragma unroll
  for (int e = 0; e < 8; ++e) {
    float ex = (base + e < n) ? __expf(vals[e] - m) : 0.f;
    vals[e] = ex; s += ex;
  }
#pragma unroll
  for (int off = 32; off > 0; off >>= 1) s += __shfl_xor(s, off, 64);
  if (lane == 0) red[4 + wave] = s;
  __syncthreads();
  s = red[4] + red[5] + red[6] + red[7];
  float inv = 1.0f / s;
  if (base < nW) {
    ushort8 o;
#pragma unroll
    for (int e = 0; e < 8; ++e) o[e] = f2bf(vals[e] * inv);   // exact zeros for idx >= n
    *(ushort8*)(srow + base) = o;
  }
}

// ---------------- split-K reduce: out = sum of 4 partials ----------------
__global__ __launch_bounds__(256) void reduce_k4(const float4* __restrict__ p,
                                                 float4* __restrict__ out, int n4) {
  int i = blockIdx.x * 256 + threadIdx.x;
  if (i >= n4) return;
  float4 a = p[i], b = p[i + n4], c = p[i + 2 * n4], d = p[i + 3 * n4];
  float4 o;
  o.x = (a.x + b.x) + (c.x + d.x);
  o.y = (a.y + b.y) + (c.y + d.y);
  o.z = (a.z + b.z) + (c.z + d.z);
  o.w = (a.w + b.w) + (c.w + d.w);
  out[i] = o;
}

// ---------------- bf16 GEMM: C = A * B^T   (A:[M,K] lda, B:[N,K] ldb, row-major bf16) ----------------
// m97 structure: 128x128 tile, BK=64, 4 waves of 64x64, mfma_f32_16x16x32_bf16, global_load_lds w16.
template<int OUT_F32, int CSKIP, int KCLIP>
__global__ __launch_bounds__(256, 2) void gemm_bt(
    const unsigned short* __restrict__ A, const unsigned short* __restrict__ B,
    void* __restrict__ C, int K, int lda, int ldb, int ldc, int nH,
    long long sAb, long long sAh, long long sBb, long long sBh,
    long long sCb, long long sCh, float scale)
{
  __shared__ unsigned short As[128 * 64];
  __shared__ unsigned short Bs[128 * 64];
  int m0 = blockIdx.y * 128, n0 = blockIdx.x * 128;
  if (CSKIP && n0 > m0) return;                 // fully-masked causal tile
  int z = blockIdx.z;
  int zb = z / nH, zh = z - zb * nH;
  const unsigned short* Ap = A + (size_t)(zb * sAb + zh * sAh);
  const unsigned short* Bp = B + (size_t)(zb * sBb + zh * sBh);
  size_t coff = (size_t)(zb * sCb + zh * sCh);
  int tid = threadIdx.x;
  int wave = tid >> 6, lane = tid & 63;
  int kEnd = KCLIP ? min(K, m0 + 128) : K;

  int wr = (wave >> 1) * 64, wc = (wave & 1) * 64;  // 2x2 wave grid, 64x64 each
  int lr = lane & 15;
  int lkb = (lane >> 4) * 8;

  f32x4 acc[4][4] = {};

  for (int k0 = 0; k0 < kEnd; k0 += 64) {
#pragma unroll
    for (int it = 0; it < 4; ++it) {
      int g = it * 256 + tid;                  // granule 0..1023 (16B each)
      int r = g >> 3, c = (g & 7) << 3;
      LDS_ASYNC16(Ap + (size_t)(m0 + r) * lda + (k0 + c), As + (size_t)(it * 256 + wave * 64) * 8);
      LDS_ASYNC16(Bp + (size_t)(n0 + r) * ldb + (k0 + c), Bs + (size_t)(it * 256 + wave * 64) * 8);
    }
    __syncthreads();
#pragma unroll
    for (int kk = 0; kk < 64; kk += 32) {
      short8 a[4], b[4];
#pragma unroll
      for (int i = 0; i < 4; ++i)
        a[i] = *(const short8*)(As + (size_t)(wr + i * 16 + lr) * 64 + kk + lkb);
#pragma unroll
      for (int j = 0; j < 4; ++j)
        b[j] = *(const short8*)(Bs + (size_t)(wc + j * 16 + lr) * 64 + kk + lkb);
#pragma unroll
      for (int i = 0; i < 4; ++i)
#pragma unroll
        for (int j = 0; j < 4; ++j)
          acc[i][j] = __builtin_amdgcn_mfma_f32_16x16x32_bf16(a[i], b[j], acc[i][j], 0, 0, 0);
    }
    __syncthreads();
  }

  int orow = (lane >> 4) * 4, ocol = lane & 15;   // C/D: col=lane&15, row=(lane>>4)*4+reg
#pragma unroll
  for (int i = 0; i < 4; ++i)
#pragma unroll
    for (int j = 0; j < 4; ++j)
#pragma unroll
      for (int r = 0; r < 4; ++r) {
        int row = m0 + wr + i * 16 + orow + r;
        int col = n0 + wc + j * 16 + ocol;
        float v = acc[i][j][r] * scale;
        if (OUT_F32) ((float*)C)[coff + (size_t)row * ldc + col] = v;
        else ((unsigned short*)C)[coff + (size_t)row * ldc + col] = f2bf(v);
      }
}

// ---------------- launcher ----------------
extern "C" void kernel_launch(void* const* d_in, const int* in_sizes, int n_in,
                              void* d_out, int out_size, void* d_ws, size_t ws_size,
                              hipStream_t stream) {
  const float* x  = (const float*)d_in[0];
  // d_in[1] = attn_mask (causal; handled analytically)
  const float* Wq = (const float*)d_in[2];
  const float* Wk = (const float*)d_in[3];
  const float* Wv = (const float*)d_in[4];
  const float* Wo = (const float*)d_in[5];

  // workspace layout (MiB, 188 total — proven budget):
  //  [0,4)    xb   bf16 [4096][512]      (dead after proj; Vt overlays [0,16))
  //  [4,16)   Wqkv bf16 [3][4096][512]   (dead after proj)
  //  [16,20)  Wob  bf16 [512][4096]
  //  [20,116) QKV  bf16 [3][4096][4096]  (Q region doubles as attention-out AO)
  //  [116,180) Sc  bf16 [8][2048][2048]  per-batch scores->P   (dead after PV;
  //            out-proj split-K partials fp32 [4][4096][512] = 32 MiB reuse [116,148))
  //  [0,16)   Vt   bf16 [8][512][2048]   per-batch transposed V (post-proj overlay)
  if (ws_size < (size_t)188 * (1 << 20)) return;   // graceful diagnostic (d_out stays 0)

  char* ws = (char*)d_ws;
  unsigned short* xb   = (unsigned short*)(ws);
  unsigned short* Wob  = (unsigned short*)(ws + (size_t)16  * (1 << 20));
  unsigned short* QKV  = (unsigned short*)(ws + (size_t)20  * (1 << 20));
  unsigned short* Sc   = (unsigned short*)(ws + (size_t)116 * (1 << 20));
  unsigned short* Vt   = (unsigned short*)(ws);                      // overlays xb+Wqkv post-proj
  float*          Pp   = (float*)(ws + (size_t)116 * (1 << 20));     // split-K partials

  const int NEw = 4096 * 512;       // elements per weight matrix / x
  const long long NEm = 4096LL * 4096;  // elements per Q/K/V matrix

  // 1) fused casts: x, Wq, Wk, Wv, Wo -> bf16 [5 regions contiguous from ws+0]
  cast5_f32_bf16<<<dim3(1024, 1, 5), 256, 0, stream>>>(x, Wq, Wk, Wv, Wo, xb);

  // 2) QKV projection: [4096,512] x [4096,512]^T -> [3][4096][4096] bf16
  gemm_bt<0, 0, 0><<<dim3(32, 32, 3), 256, 0, stream>>>(
      xb, xb + NEw, QKV, 512, 512, 512, 4096, 3,
      0LL, 0LL, 0LL, (long long)NEw, 0LL, NEm, 1.0f);

  // 3) attention, 2 groups = batch b, 8 heads each (slot zh = head)
  for (int b = 0; b < 2; ++b) {
    size_t tokOff = (size_t)b * 2048 * 4096;
    const unsigned short* Qb = QKV + tokOff;
    const unsigned short* Kb = QKV + NEm + tokOff;
    const unsigned short* Vb = QKV + 2 * NEm + tokOff;
    unsigned short* AOb = QKV + tokOff;              // AO aliases Q (per-head Q dead after scores)

    // 3a) scores = Q K^T / sqrt(512) -> bf16, causal tile skip
    gemm_bt<0, 1, 0><<<dim3(16, 16, 8), 256, 0, stream>>>(
        Qb, Kb, Sc, 512, 4096, 4096, 2048, 8,
        0LL, 512LL, 0LL, 512LL, 0LL, 2048LL * 2048, 0.04419417382415922f);

    // 3b) V transpose, all 8 heads
    transpose_v<<<dim3(32, 8, 8), 256, 0, stream>>>(Vb, Vt);

    // 3c) softmax (causal) bf16 -> bf16 P in place
    softmax_causal_bf16<<<dim3(8 * 2048), 256, 0, stream>>>(Sc);

    // 3d) O = P @ V via P * Vt^T, k clipped to m0+128
    gemm_bt<0, 0, 1><<<dim3(4, 16, 8), 256, 0, stream>>>(
        Sc, Vt, AOb, 2048, 2048, 2048, 4096, 8,
        0LL, 2048LL * 2048, 0LL, 512LL * 2048, 0LL, 512LL, 1.0f);
  }

  // 4) out-proj split-K=4: partial[z] = AO[:, z*1024 +: 1024] @ Wob[:, z*1024 +: 1024]^T
  gemm_bt<1, 0, 0><<<dim3(4, 32, 4), 256, 0, stream>>>(
      QKV, Wob, Pp, 1024, 4096, 4096, 512, 4,
      0LL, 1024LL, 0LL, 1024LL, 0LL, 2097152LL, 1.0f);

  // 5) reduce partials -> fp32 d_out [4096][512]
  reduce_k4<<<dim3(2048), 256, 0, stream>>>((const float4*)Pp, (float4*)d_out, 524288);
}